// Round 9
// baseline (129.934 us; speedup 1.0000x reference)
//
#include <hip/hip_runtime.h>
#include <math.h>

// B=64, T=512, C=384, H=64. fp32 in/out; bf16 MFMA internally.
#define NB 64
#define NT 512
#define NC 384
#define NH 64

typedef __attribute__((ext_vector_type(8))) short bf16x8;
typedef __attribute__((ext_vector_type(4))) float f32x4;

__device__ __forceinline__ unsigned short f2bf(float f) {
  unsigned int u = __float_as_uint(f);
  return (unsigned short)((u + 0x7FFFu + ((u >> 16) & 1u)) >> 16);
}
__device__ __forceinline__ unsigned int pk2bf(float a, float b) {
  return (unsigned int)f2bf(a) | ((unsigned int)f2bf(b) << 16);
}

// ---------------------------------------------------------------------------
// Kernel 0: W[384][64] fp32 x3 -> Wt[192][384] bf16 (transposed, row-major)
// ---------------------------------------------------------------------------
__global__ __launch_bounds__(256) void wtrans_kernel(
    const float* __restrict__ Wq, const float* __restrict__ Wk,
    const float* __restrict__ Wv, unsigned short* __restrict__ Wt) {
  int id = blockIdx.x * 256 + threadIdx.x;
  if (id >= 3 * NC * NH) return;
  int m = id / (NC * NH);
  int r = id % (NC * NH);
  int c = r / NH;
  int h = r % NH;
  const float* W = (m == 0) ? Wq : ((m == 1) ? Wk : Wv);
  Wt[(m * NH + h) * NC + c] = f2bf(W[c * NH + h]);
}

// ---------------------------------------------------------------------------
// Kernel 1: fused QKV projection. M=32768, K=384, N=192.
// r9: 32-ROW tiles, grid 1024 (was 64-row/512) — finer pipeline granularity
// so staging of one block overlaps compute/epilogue of the co-resident one.
// 6 waves; wave w owns N-tiles {2w,2w+1}; 24 wave-resident B-frags loaded
// from L2 once (latency hidden by the single staging barrier). K-loop =
// LDS A-frag reads + MFMA only. ONE barrier total.
// ---------------------------------------------------------------------------
#define XS 392  // row stride in ushorts (784 B, 16B-aligned)
__global__ __launch_bounds__(384, 3) void proj_kernel(
    const float* __restrict__ x, const unsigned short* __restrict__ Wt,
    unsigned short* __restrict__ q, unsigned short* __restrict__ k,
    unsigned short* __restrict__ vt) {
  __shared__ unsigned short xs[32 * XS];  // 25088 B
  const int t = threadIdx.x;  // 0..383
  const int m0 = blockIdx.x * 32;
  const int w = t / 64, l = t & 63, mi = l & 15, quad = l >> 4;

  // stage x tile: 32 rows x 384 fp32 -> bf16 (coalesced float4)
#pragma unroll
  for (int i = 0; i < 8; ++i) {
    int u = t + i * 384;  // 0..3071; row = u/96, 4-float seg = u%96
    int row = u / 96;
    int cp = (u % 96) * 4;
    float4 a = *(const float4*)(x + (size_t)(m0 + row) * NC + cp);
    ushort4 bb;
    bb.x = f2bf(a.x); bb.y = f2bf(a.y); bb.z = f2bf(a.z); bb.w = f2bf(a.w);
    *(ushort4*)&xs[row * XS + cp] = bb;
  }

  // wave-resident B-frags: tiles 2w, 2w+1 (in flight alongside staging)
  bf16x8 bfr[2][12];
#pragma unroll
  for (int ntl = 0; ntl < 2; ++ntl) {
    const unsigned short* wr =
        Wt + (size_t)((w * 2 + ntl) * 16 + mi) * NC + quad * 8;
#pragma unroll
    for (int kc = 0; kc < 12; ++kc)
      bfr[ntl][kc] = *(const bf16x8*)(wr + kc * 32);
  }
  __syncthreads();

  f32x4 acc[2][2];  // [ntl][msub]
  const f32x4 zero = {0.f, 0.f, 0.f, 0.f};
#pragma unroll
  for (int i = 0; i < 2; ++i)
#pragma unroll
    for (int j = 0; j < 2; ++j) acc[i][j] = zero;

#pragma unroll
  for (int msub = 0; msub < 2; ++msub) {
#pragma unroll
    for (int kc = 0; kc < 12; ++kc) {
      bf16x8 a = *(const bf16x8*)&xs[(msub * 16 + mi) * XS + kc * 32 + quad * 8];
      acc[0][msub] =
          __builtin_amdgcn_mfma_f32_16x16x32_bf16(a, bfr[0][kc], acc[0][msub], 0, 0, 0);
      acc[1][msub] =
          __builtin_amdgcn_mfma_f32_16x16x32_bf16(a, bfr[1][kc], acc[1][msub], 0, 0, 0);
    }
  }

  // epilogue: C/D col=mi, row=quad*4+r. Tile=2w+ntl; matrix=tile>>2.
  if (w < 4) {
    unsigned short* dst = (w < 2) ? q : k;
    const float sc = (w < 2) ? 0.125f : 1.0f;  // fold 1/sqrt(64), exact
#pragma unroll
    for (int ntl = 0; ntl < 2; ++ntl) {
      int tile = w * 2 + ntl;
      int h = (tile & 3) * 16 + mi;
#pragma unroll
      for (int msub = 0; msub < 2; ++msub)
#pragma unroll
        for (int r = 0; r < 4; ++r)
          dst[(size_t)(m0 + msub * 16 + quad * 4 + r) * NH + h] =
              f2bf(acc[ntl][msub][r] * sc);
    }
  } else {  // v: 4 consecutive tokens per lane -> ushort4 into vt[b][h][t]
    int bb = m0 >> 9, t0 = m0 & 511;
#pragma unroll
    for (int ntl = 0; ntl < 2; ++ntl) {
      int tile = w * 2 + ntl;
      int h = (tile & 3) * 16 + mi;
#pragma unroll
      for (int msub = 0; msub < 2; ++msub) {
        ushort4 s;
        s.x = f2bf(acc[ntl][msub][0]);
        s.y = f2bf(acc[ntl][msub][1]);
        s.z = f2bf(acc[ntl][msub][2]);
        s.w = f2bf(acc[ntl][msub][3]);
        *(ushort4*)&vt[((size_t)bb * NH + h) * NT + t0 + msub * 16 + quad * 4] = s;
      }
    }
  }
}

// ---------------------------------------------------------------------------
// Kernel 2: causal flash attention (r7 form — best measured). ONE WAVE per
// (b, 16-row q-tile). Fragments gathered from L2-hot global, 16 loads in
// flight per k-tile; P round-trip via wave-local LDS; zero barriers.
// ---------------------------------------------------------------------------
#define PSTR 72
__global__ __launch_bounds__(64) void attn_kernel(
    const unsigned short* __restrict__ q, const unsigned short* __restrict__ k,
    const unsigned short* __restrict__ vt, float* __restrict__ out) {
  __shared__ unsigned short ps[16 * PSTR];
  const int l = threadIdx.x;
  const int mi = l & 15, quad = l >> 4;
  const int bx = blockIdx.x;
  const int qi = 31 - (bx >> 6);  // heavy tiles first
  const int b = bx & 63;

  const unsigned short* qrow = q + ((size_t)b * NT + qi * 16 + mi) * NH;
  bf16x8 qb0 = *(const bf16x8*)(qrow + quad * 8);
  bf16x8 qb1 = *(const bf16x8*)(qrow + 32 + quad * 8);

  f32x4 accO[4];
  const f32x4 zero = {0.f, 0.f, 0.f, 0.f};
#pragma unroll
  for (int i = 0; i < 4; ++i) accO[i] = zero;
  float mrow = -INFINITY, lrow = 0.f;  // per-lane q-row = qi*16 + mi

  const int ktmax = (qi * 16 + 15) >> 6;
  for (int kt = 0; kt <= ktmax; ++kt) {
    const unsigned short* kb = k + ((size_t)b * NT + kt * 64) * NH;
    const unsigned short* vb = vt + (size_t)b * NH * NT + kt * 64;
    bf16x8 ka0[4], ka1[4], va0[4], va1[4];
#pragma unroll
    for (int nt = 0; nt < 4; ++nt) {
      const unsigned short* kr = kb + (size_t)(nt * 16 + mi) * NH + quad * 8;
      ka0[nt] = *(const bf16x8*)kr;
      ka1[nt] = *(const bf16x8*)(kr + 32);
      const unsigned short* vr = vb + (size_t)(nt * 16 + mi) * NT + quad * 8;
      va0[nt] = *(const bf16x8*)vr;
      va1[nt] = *(const bf16x8*)(vr + 32);
    }

    // S^T tile: A = K rows (m=key), B = Q rows (n=q).
    float p[4][4];
#pragma unroll
    for (int nt = 0; nt < 4; ++nt) {
      f32x4 z = zero;
      z = __builtin_amdgcn_mfma_f32_16x16x32_bf16(ka0[nt], qb0, z, 0, 0, 0);
      z = __builtin_amdgcn_mfma_f32_16x16x32_bf16(ka1[nt], qb1, z, 0, 0, 0);
#pragma unroll
      for (int r = 0; r < 4; ++r) p[nt][r] = z[r];
    }

    if (kt == ktmax) {  // causal mask on diagonal tile
#pragma unroll
      for (int nt = 0; nt < 4; ++nt)
#pragma unroll
        for (int r = 0; r < 4; ++r)
          if (kt * 64 + nt * 16 + quad * 4 + r > qi * 16 + mi)
            p[nt][r] = -INFINITY;
    }

    // online softmax for q=mi (keys spread across quads)
    float vmax = -INFINITY;
#pragma unroll
    for (int nt = 0; nt < 4; ++nt)
#pragma unroll
      for (int r = 0; r < 4; ++r) vmax = fmaxf(vmax, p[nt][r]);
    vmax = fmaxf(vmax, __shfl_xor(vmax, 16));
    vmax = fmaxf(vmax, __shfl_xor(vmax, 32));
    float mn = fmaxf(mrow, vmax);
    float alpha = __expf(mrow - mn);
    mrow = mn;

    float rsum = 0.f;
#pragma unroll
    for (int nt = 0; nt < 4; ++nt)
#pragma unroll
      for (int r = 0; r < 4; ++r) {
        p[nt][r] = __expf(p[nt][r] - mn);
        rsum += p[nt][r];
      }
    rsum += __shfl_xor(rsum, 16);
    rsum += __shfl_xor(rsum, 32);
    lrow = lrow * alpha + rsum;

    // P -> LDS (row-contiguous, wave-local, no barrier) -> A-frags
#pragma unroll
    for (int nt = 0; nt < 4; ++nt) {
      uint2 pk;
      pk.x = pk2bf(p[nt][0], p[nt][1]);
      pk.y = pk2bf(p[nt][2], p[nt][3]);
      *(uint2*)&ps[mi * PSTR + nt * 16 + quad * 4] = pk;
    }
    bf16x8 pa0 = *(const bf16x8*)&ps[mi * PSTR + quad * 8];
    bf16x8 pa1 = *(const bf16x8*)&ps[mi * PSTR + 32 + quad * 8];

    float av[4];
#pragma unroll
    for (int r = 0; r < 4; ++r) av[r] = __shfl(alpha, quad * 4 + r);
#pragma unroll
    for (int hi = 0; hi < 4; ++hi)
#pragma unroll
      for (int r = 0; r < 4; ++r) accO[hi][r] *= av[r];

    // O += P V  (A = P rows, B = V^T rows; D col=h, row=q)
#pragma unroll
    for (int hi = 0; hi < 4; ++hi) {
      accO[hi] = __builtin_amdgcn_mfma_f32_16x16x32_bf16(pa0, va0[hi], accO[hi], 0, 0, 0);
      accO[hi] = __builtin_amdgcn_mfma_f32_16x16x32_bf16(pa1, va1[hi], accO[hi], 0, 0, 0);
    }
  }

  // epilogue
  float inv = 1.f / lrow;
  const size_t obase = ((size_t)b * NT + qi * 16) * NH;
#pragma unroll
  for (int r = 0; r < 4; ++r) {
    float iv = __shfl(inv, quad * 4 + r);
#pragma unroll
    for (int hi = 0; hi < 4; ++hi)
      out[obase + (size_t)(quad * 4 + r) * NH + hi * 16 + mi] = accO[hi][r] * iv;
  }
}

extern "C" void kernel_launch(void* const* d_in, const int* in_sizes, int n_in,
                              void* d_out, int out_size, void* d_ws, size_t ws_size,
                              hipStream_t stream) {
  const float* x  = (const float*)d_in[0];
  const float* Wq = (const float*)d_in[1];
  const float* Wk = (const float*)d_in[2];
  const float* Wv = (const float*)d_in[3];

  unsigned short* Wt = (unsigned short*)d_ws;          // 192*384
  unsigned short* qb = Wt + 192 * 384;                 // 32768*64 each
  unsigned short* kb = qb + 32768 * 64;
  unsigned short* vtb = kb + 32768 * 64;               // Vt[b][h][t]
  float* out = (float*)d_out;

  wtrans_kernel<<<288, 256, 0, stream>>>(Wq, Wk, Wv, Wt);
  proj_kernel<<<1024, 384, 0, stream>>>(x, Wt, qb, kb, vtb);
  attn_kernel<<<2048, 64, 0, stream>>>(qb, kb, vtb, out);
}

// Round 11
// 122.987 us; speedup vs baseline: 1.0565x; 1.0565x over previous
//
#include <hip/hip_runtime.h>
#include <math.h>

// B=64, T=512, C=384, H=64. fp32 in/out; bf16 MFMA internally.
#define NB 64
#define NT 512
#define NC 384
#define NH 64

typedef __attribute__((ext_vector_type(8))) short bf16x8;
typedef __attribute__((ext_vector_type(4))) float f32x4;

__device__ __forceinline__ unsigned short f2bf(float f) {
  unsigned int u = __float_as_uint(f);
  return (unsigned short)((u + 0x7FFFu + ((u >> 16) & 1u)) >> 16);
}
__device__ __forceinline__ unsigned int pk2bf(float a, float b) {
  return (unsigned int)f2bf(a) | ((unsigned int)f2bf(b) << 16);
}

// ---------------------------------------------------------------------------
// Kernel 0: W[384][64] fp32 x3 -> Wt[192][384] bf16 (transposed, row-major)
// ---------------------------------------------------------------------------
__global__ __launch_bounds__(256) void wtrans_kernel(
    const float* __restrict__ Wq, const float* __restrict__ Wk,
    const float* __restrict__ Wv, unsigned short* __restrict__ Wt) {
  int id = blockIdx.x * 256 + threadIdx.x;
  if (id >= 3 * NC * NH) return;
  int m = id / (NC * NH);
  int r = id % (NC * NH);
  int c = r / NH;
  int h = r % NH;
  const float* W = (m == 0) ? Wq : ((m == 1) ? Wk : Wv);
  Wt[(m * NH + h) * NC + c] = f2bf(W[c * NH + h]);
}

// ---------------------------------------------------------------------------
// Kernel 1: fused QKV projection (r7 form — best measured, unchanged).
// ---------------------------------------------------------------------------
#define XS 392  // 64 rows x 392 ushorts; 784 B row stride
__global__ __launch_bounds__(384, 3) void proj_kernel(
    const float* __restrict__ x, const unsigned short* __restrict__ Wt,
    unsigned short* __restrict__ q, unsigned short* __restrict__ k,
    unsigned short* __restrict__ vt) {
  __shared__ unsigned short xs[64 * XS];  // 50176 B
  const int t = threadIdx.x;  // 0..383
  const int m0 = blockIdx.x * 64;
  const int w = t / 64, l = t & 63, mi = l & 15, quad = l >> 4;

  // stage x tile: 64 rows x 384 fp32 -> bf16 (coalesced float4)
#pragma unroll 4
  for (int i = 0; i < 16; ++i) {
    int u = t + i * 384;
    int row = u / 96;
    int cp = (u % 96) * 4;
    float4 a = *(const float4*)(x + (size_t)(m0 + row) * NC + cp);
    ushort4 bb;
    bb.x = f2bf(a.x); bb.y = f2bf(a.y); bb.z = f2bf(a.z); bb.w = f2bf(a.w);
    *(ushort4*)&xs[row * XS + cp] = bb;
  }

  // wave-resident B-frags: tiles 2w, 2w+1
  bf16x8 bfr[2][12];
#pragma unroll
  for (int ntl = 0; ntl < 2; ++ntl) {
    const unsigned short* wr =
        Wt + (size_t)((w * 2 + ntl) * 16 + mi) * NC + quad * 8;
#pragma unroll
    for (int kc = 0; kc < 12; ++kc)
      bfr[ntl][kc] = *(const bf16x8*)(wr + kc * 32);
  }
  __syncthreads();

  f32x4 acc[2][4];  // [ntl][msub]
  const f32x4 zero = {0.f, 0.f, 0.f, 0.f};
#pragma unroll
  for (int i = 0; i < 2; ++i)
#pragma unroll
    for (int j = 0; j < 4; ++j) acc[i][j] = zero;

#pragma unroll
  for (int msub = 0; msub < 4; ++msub) {
#pragma unroll
    for (int kc = 0; kc < 12; ++kc) {
      bf16x8 a = *(const bf16x8*)&xs[(msub * 16 + mi) * XS + kc * 32 + quad * 8];
      acc[0][msub] =
          __builtin_amdgcn_mfma_f32_16x16x32_bf16(a, bfr[0][kc], acc[0][msub], 0, 0, 0);
      acc[1][msub] =
          __builtin_amdgcn_mfma_f32_16x16x32_bf16(a, bfr[1][kc], acc[1][msub], 0, 0, 0);
    }
  }

  // epilogue: C/D col=mi, row=quad*4+r. Tile=2w+ntl; matrix=tile>>2.
  if (w < 4) {
    unsigned short* dst = (w < 2) ? q : k;
    const float sc = (w < 2) ? 0.125f : 1.0f;  // fold 1/sqrt(64), exact
#pragma unroll
    for (int ntl = 0; ntl < 2; ++ntl) {
      int tile = w * 2 + ntl;
      int h = (tile & 3) * 16 + mi;
#pragma unroll
      for (int msub = 0; msub < 4; ++msub)
#pragma unroll
        for (int r = 0; r < 4; ++r)
          dst[(size_t)(m0 + msub * 16 + quad * 4 + r) * NH + h] =
              f2bf(acc[ntl][msub][r] * sc);
    }
  } else {  // v: 4 consecutive tokens per lane -> ushort4 into vt[b][h][t]
    int bb = m0 >> 9, t0 = m0 & 511;
#pragma unroll
    for (int ntl = 0; ntl < 2; ++ntl) {
      int tile = w * 2 + ntl;
      int h = (tile & 3) * 16 + mi;
#pragma unroll
      for (int msub = 0; msub < 4; ++msub) {
        ushort4 s;
        s.x = f2bf(acc[ntl][msub][0]);
        s.y = f2bf(acc[ntl][msub][1]);
        s.z = f2bf(acc[ntl][msub][2]);
        s.w = f2bf(acc[ntl][msub][3]);
        *(ushort4*)&vt[((size_t)bb * NH + h) * NT + t0 + msub * 16 + quad * 4] = s;
      }
    }
  }
}

// ---------------------------------------------------------------------------
// Kernel 2: causal flash attention, SPLIT-K. Block = 128 thr = 2 waves per
// (b, 16-row q-tile). Wave s processes k-tiles kt ≡ s (mod 2) with private
// (m,l,accO); merged at the end through LDS (one barrier). Serial chain per
// wave halved vs r7; total waves 2048 -> 4096.
// ---------------------------------------------------------------------------
#define PSTR 72
__global__ __launch_bounds__(128) void attn_kernel(
    const unsigned short* __restrict__ q, const unsigned short* __restrict__ k,
    const unsigned short* __restrict__ vt, float* __restrict__ out) {
  __shared__ unsigned short ps[2][16 * PSTR];  // per-wave P round-trip
  __shared__ float obuf[16 * 64];              // wave1 accO for merge
  __shared__ float mlbuf[2][16];               // wave1 m,l per q-row

  const int t = threadIdx.x;
  const int w = t >> 6;        // 0 or 1: K-split index
  const int l = t & 63;
  const int mi = l & 15, quad = l >> 4;
  const int bx = blockIdx.x;
  const int qi = 31 - (bx >> 6);  // heavy q-tiles first
  const int b = bx & 63;

  const unsigned short* qrow = q + ((size_t)b * NT + qi * 16 + mi) * NH;
  bf16x8 qb0 = *(const bf16x8*)(qrow + quad * 8);
  bf16x8 qb1 = *(const bf16x8*)(qrow + 32 + quad * 8);

  f32x4 accO[4];
  const f32x4 zero = {0.f, 0.f, 0.f, 0.f};
#pragma unroll
  for (int i = 0; i < 4; ++i) accO[i] = zero;
  float mrow = -INFINITY, lrow = 0.f;  // per-lane q-row = qi*16 + mi

  const int ktmax = (qi * 16 + 15) >> 6;
  for (int kt = w; kt <= ktmax; kt += 2) {
    const unsigned short* kb = k + ((size_t)b * NT + kt * 64) * NH;
    const unsigned short* vb = vt + (size_t)b * NH * NT + kt * 64;
    bf16x8 ka0[4], ka1[4], va0[4], va1[4];
#pragma unroll
    for (int nt = 0; nt < 4; ++nt) {
      const unsigned short* kr = kb + (size_t)(nt * 16 + mi) * NH + quad * 8;
      ka0[nt] = *(const bf16x8*)kr;
      ka1[nt] = *(const bf16x8*)(kr + 32);
      const unsigned short* vr = vb + (size_t)(nt * 16 + mi) * NT + quad * 8;
      va0[nt] = *(const bf16x8*)vr;
      va1[nt] = *(const bf16x8*)(vr + 32);
    }

    // S^T tile: A = K rows (m=key), B = Q rows (n=q).
    float p[4][4];
#pragma unroll
    for (int nt = 0; nt < 4; ++nt) {
      f32x4 z = zero;
      z = __builtin_amdgcn_mfma_f32_16x16x32_bf16(ka0[nt], qb0, z, 0, 0, 0);
      z = __builtin_amdgcn_mfma_f32_16x16x32_bf16(ka1[nt], qb1, z, 0, 0, 0);
#pragma unroll
      for (int r = 0; r < 4; ++r) p[nt][r] = z[r];
    }

    if (kt == ktmax) {  // causal mask on diagonal tile
#pragma unroll
      for (int nt = 0; nt < 4; ++nt)
#pragma unroll
        for (int r = 0; r < 4; ++r)
          if (kt * 64 + nt * 16 + quad * 4 + r > qi * 16 + mi)
            p[nt][r] = -INFINITY;
    }

    // online softmax for q=mi (keys spread across quads)
    float vmax = -INFINITY;
#pragma unroll
    for (int nt = 0; nt < 4; ++nt)
#pragma unroll
      for (int r = 0; r < 4; ++r) vmax = fmaxf(vmax, p[nt][r]);
    vmax = fmaxf(vmax, __shfl_xor(vmax, 16));
    vmax = fmaxf(vmax, __shfl_xor(vmax, 32));
    float mn = fmaxf(mrow, vmax);
    float alpha = __expf(mrow - mn);
    mrow = mn;

    float rsum = 0.f;
#pragma unroll
    for (int nt = 0; nt < 4; ++nt)
#pragma unroll
      for (int r = 0; r < 4; ++r) {
        p[nt][r] = __expf(p[nt][r] - mn);
        rsum += p[nt][r];
      }
    rsum += __shfl_xor(rsum, 16);
    rsum += __shfl_xor(rsum, 32);
    lrow = lrow * alpha + rsum;

    // P -> LDS (row-contiguous, wave-local, no barrier) -> A-frags
#pragma unroll
    for (int nt = 0; nt < 4; ++nt) {
      uint2 pk;
      pk.x = pk2bf(p[nt][0], p[nt][1]);
      pk.y = pk2bf(p[nt][2], p[nt][3]);
      *(uint2*)&ps[w][mi * PSTR + nt * 16 + quad * 4] = pk;
    }
    bf16x8 pa0 = *(const bf16x8*)&ps[w][mi * PSTR + quad * 8];
    bf16x8 pa1 = *(const bf16x8*)&ps[w][mi * PSTR + 32 + quad * 8];

    float av[4];
#pragma unroll
    for (int r = 0; r < 4; ++r) av[r] = __shfl(alpha, quad * 4 + r);
#pragma unroll
    for (int hi = 0; hi < 4; ++hi)
#pragma unroll
      for (int r = 0; r < 4; ++r) accO[hi][r] *= av[r];

    // O += P V  (A = P rows, B = V^T rows; D col=h, row=q)
#pragma unroll
    for (int hi = 0; hi < 4; ++hi) {
      accO[hi] = __builtin_amdgcn_mfma_f32_16x16x32_bf16(pa0, va0[hi], accO[hi], 0, 0, 0);
      accO[hi] = __builtin_amdgcn_mfma_f32_16x16x32_bf16(pa1, va1[hi], accO[hi], 0, 0, 0);
    }
  }

  // ---- merge the two K-split halves ----
  if (w == 1) {
#pragma unroll
    for (int hi = 0; hi < 4; ++hi)
#pragma unroll
      for (int r = 0; r < 4; ++r)
        obuf[(quad * 4 + r) * 64 + hi * 16 + mi] = accO[hi][r];
    if (quad == 0) {
      mlbuf[0][mi] = mrow;
      mlbuf[1][mi] = lrow;
    }
  }
  __syncthreads();
  if (w == 0) {
    // per-lane state is for q-row = mi (replicated across quads)
    float m1 = mlbuf[0][mi], l1 = mlbuf[1][mi];
    float mf = fmaxf(mrow, m1);           // mrow finite (wave0 owns kt=0)
    float a0 = __expf(mrow - mf);
    float a1 = __expf(m1 - mf);           // 0 if wave1 had no tiles
    float lf = a0 * lrow + a1 * l1;
    float inv = 1.f / lf;

    const size_t obase = ((size_t)b * NT + qi * 16) * NH;
#pragma unroll
    for (int r = 0; r < 4; ++r) {
      float a0r = __shfl(a0, quad * 4 + r);
      float a1r = __shfl(a1, quad * 4 + r);
      float ivr = __shfl(inv, quad * 4 + r);
#pragma unroll
      for (int hi = 0; hi < 4; ++hi) {
        float o1 = obuf[(quad * 4 + r) * 64 + hi * 16 + mi];
        out[obase + (size_t)(quad * 4 + r) * NH + hi * 16 + mi] =
            (a0r * accO[hi][r] + a1r * o1) * ivr;
      }
    }
  }
}

extern "C" void kernel_launch(void* const* d_in, const int* in_sizes, int n_in,
                              void* d_out, int out_size, void* d_ws, size_t ws_size,
                              hipStream_t stream) {
  const float* x  = (const float*)d_in[0];
  const float* Wq = (const float*)d_in[1];
  const float* Wk = (const float*)d_in[2];
  const float* Wv = (const float*)d_in[3];

  unsigned short* Wt = (unsigned short*)d_ws;          // 192*384
  unsigned short* qb = Wt + 192 * 384;                 // 32768*64 each
  unsigned short* kb = qb + 32768 * 64;
  unsigned short* vtb = kb + 32768 * 64;               // Vt[b][h][t]
  float* out = (float*)d_out;

  wtrans_kernel<<<288, 256, 0, stream>>>(Wq, Wk, Wv, Wt);
  proj_kernel<<<512, 384, 0, stream>>>(x, Wt, qb, kb, vtb);
  attn_kernel<<<2048, 128, 0, stream>>>(qb, kb, vtb, out);
}